// Round 7
// baseline (671.260 us; speedup 1.0000x reference)
//
#include <hip/hip_runtime.h>
#include <hip/hip_bf16.h>

typedef float f32x4 __attribute__((ext_vector_type(4)));

#define BATCH 32
#define S_LEN 4095
#define SEQ   4096
#define E_DIM 1024
#define NH    16
#define HD    64
#define CHUNK 64
#define NCH   64          // chunks per batch
#define NBLK  512         // persistent blocks
#define NTASK (BATCH * NCH)   // 2048

__device__ __forceinline__ void ntstore4(float* p, f32x4 v) {
    __builtin_nontemporal_store(v, (f32x4*)p);
}

// -------- kernel 0: last-valid index + fused mask/bias per batch --------
__global__ __launch_bounds__(256) void prep_kernel(const int* __restrict__ mask,
                                                   const float* __restrict__ bias,
                                                   int* __restrict__ lastbuf,
                                                   float* __restrict__ mbias) {
    int b = blockIdx.x;
    int t = threadIdx.x;
    int best = -1;
    for (int s = t; s < SEQ; s += 256) {
        int mv = mask[b * SEQ + s];
        mbias[b * SEQ + s] = mv ? bias[s] : -1.0e9f;
        if (mv) best = max(best, s);
    }
    __shared__ int red[256];
    red[t] = best;
    __syncthreads();
    for (int o = 128; o > 0; o >>= 1) {
        if (t < o) red[t] = max(red[t], red[t + o]);
        __syncthreads();
    }
    if (t == 0) lastbuf[b] = (red[0] < 0) ? (SEQ - 1) : red[0];
}

// -------- kernel 1: qkv = h @ c_attn_w + c_attn_b, 4-way k-sliced --------
__global__ __launch_bounds__(256) void qkv_kernel(const float* __restrict__ hs,
                                                  const float* __restrict__ W,
                                                  const float* __restrict__ bias,
                                                  float* __restrict__ qkv) {
    const int b = blockIdx.y;
    const int jj = threadIdx.x & 63;
    const int j = blockIdx.x * 64 + jj;
    const int ksl = threadIdx.x >> 6;
    __shared__ float h[E_DIM];
    for (int i = threadIdx.x; i < E_DIM; i += 256) h[i] = hs[b * E_DIM + i];
    __syncthreads();
    float acc = 0.f;
    const int k0 = ksl * 256;
    #pragma unroll 8
    for (int k = k0; k < k0 + 256; ++k) acc = fmaf(h[k], W[(size_t)k * 3072 + j], acc);
    __shared__ float red[4][64];
    red[ksl][jj] = acc;
    __syncthreads();
    if (ksl == 0)
        qkv[b * 3072 + j] = acc + red[1][jj] + red[2][jj] + red[3][jj] + bias[j];
}

// -------- kernel 2: persistent-block fused K-phase + V-phase per chunk --------
// task = blockIdx.x + NBLK*j ; b = task/NCH ; chunk = task%NCH
// Phase K: read kcache rows -> write newk, scores->exp->LDS (2 streams)
// Phase V: read vcache rows -> write newv, weighted accumulate  (2 streams)
__global__ __launch_bounds__(256) void attn_kv_kernel(
    const float* __restrict__ kcache, const float* __restrict__ vcache,
    const float* __restrict__ mbias, const float* __restrict__ qkv,
    const int* __restrict__ lastbuf,
    float* __restrict__ newk, float* __restrict__ newv,
    float* __restrict__ pl, float* __restrict__ pctx) {
    const int t = threadIdx.x;
    const int wave = t >> 6;
    const int lane = t & 63;
    const int head = wave * 4 + (lane >> 4);
    const int lig = lane & 15;
    const int col = head * HD + lig * 4;

    __shared__ float w_s[NH][CHUNK];

    for (int j = 0; j < NTASK / NBLK; ++j) {
        const int task = blockIdx.x + NBLK * j;
        const int b = task >> 6;          // task / NCH
        const int c = task & 63;          // task % NCH
        const int last = lastbuf[b];
        const int s0 = c * CHUNK;
        const bool clean = (s0 + CHUNK <= S_LEN) && (last < s0 || last >= s0 + CHUNK);

        const f32x4 q4 = *(const f32x4*)(qkv + b * 3072 + col);
        const f32x4 kn4 = *(const f32x4*)(qkv + b * 3072 + 1024 + col);
        const f32x4 vn4 = *(const f32x4*)(qkv + b * 3072 + 2048 + col);
        const float* kb = kcache + (size_t)b * S_LEN * E_DIM;
        const float* vb = vcache + (size_t)b * S_LEN * E_DIM;
        float* nkb = newk + (size_t)b * SEQ * E_DIM;
        float* nvb = newv + (size_t)b * SEQ * E_DIM;
        const float* mbb = mbias + b * SEQ;

        // ---------------- K phase ----------------
        if (clean) {
            for (int r = 0; r < CHUNK; r += 8) {
                f32x4 kk[8];
                #pragma unroll
                for (int u = 0; u < 8; ++u)
                    kk[u] = *(const f32x4*)(kb + (size_t)(s0 + r + u) * E_DIM + col);
                #pragma unroll
                for (int u = 0; u < 8; ++u)
                    ntstore4(nkb + (size_t)(s0 + r + u) * E_DIM + col, kk[u]);
                #pragma unroll
                for (int u = 0; u < 8; ++u) {
                    float p = kk[u][0] * q4[0] + kk[u][1] * q4[1] + kk[u][2] * q4[2] + kk[u][3] * q4[3];
                    p += __shfl_xor(p, 1);
                    p += __shfl_xor(p, 2);
                    p += __shfl_xor(p, 4);
                    p += __shfl_xor(p, 8);
                    if (lig == 0)
                        w_s[head][r + u] = __expf(fmaf(p, 0.125f, mbb[s0 + r + u]));
                }
            }
        } else {
            for (int r = 0; r < CHUNK; ++r) {
                const int s = s0 + r;
                f32x4 kk;
                if (s == last) kk = kn4;
                else if (s < S_LEN) kk = *(const f32x4*)(kb + (size_t)s * E_DIM + col);
                else kk = (f32x4){0.f, 0.f, 0.f, 0.f};
                ntstore4(nkb + (size_t)s * E_DIM + col, kk);
                float p = kk[0] * q4[0] + kk[1] * q4[1] + kk[2] * q4[2] + kk[3] * q4[3];
                p += __shfl_xor(p, 1);
                p += __shfl_xor(p, 2);
                p += __shfl_xor(p, 4);
                p += __shfl_xor(p, 8);
                if (lig == 0)
                    w_s[head][r] = __expf(fmaf(p, 0.125f, mbb[s]));
            }
        }
        __syncthreads();

        // ---------------- V phase ----------------
        float l = 0.f;
        f32x4 acc = (f32x4){0.f, 0.f, 0.f, 0.f};
        if (clean) {
            for (int r = 0; r < CHUNK; r += 8) {
                f32x4 vv[8];
                #pragma unroll
                for (int u = 0; u < 8; ++u)
                    vv[u] = *(const f32x4*)(vb + (size_t)(s0 + r + u) * E_DIM + col);
                #pragma unroll
                for (int u = 0; u < 8; ++u)
                    ntstore4(nvb + (size_t)(s0 + r + u) * E_DIM + col, vv[u]);
                #pragma unroll
                for (int u = 0; u < 8; ++u) {
                    const float w = w_s[head][r + u];
                    l += w;
                    acc += vv[u] * w;
                }
            }
        } else {
            for (int r = 0; r < CHUNK; ++r) {
                const int s = s0 + r;
                f32x4 vv;
                if (s == last) vv = vn4;
                else if (s < S_LEN) vv = *(const f32x4*)(vb + (size_t)s * E_DIM + col);
                else vv = (f32x4){0.f, 0.f, 0.f, 0.f};
                ntstore4(nvb + (size_t)s * E_DIM + col, vv);
                const float w = w_s[head][r];
                l += w;
                acc += vv * w;
            }
        }

        const int pidx = (b * NH + head) * NCH + c;
        if (lig == 0) pl[pidx] = l;
        *(f32x4*)(pctx + (size_t)pidx * HD + lig * 4) = acc;
        __syncthreads();   // protect w_s before next task overwrites it
    }
}

// -------- kernel 3: reduce chunk partials per (b,h) --------
__global__ __launch_bounds__(256) void reduce_kernel(const float* __restrict__ pl,
                                                     const float* __restrict__ pctx,
                                                     float* __restrict__ ctxout,
                                                     int nchunk) {
    const int gw = (blockIdx.x * blockDim.x + threadIdx.x) >> 6;
    const int lane = threadIdx.x & 63;
    if (gw >= BATCH * NH) return;
    float lacc = 0.f, cacc = 0.f;
    for (int c = 0; c < nchunk; ++c) {
        lacc += pl[gw * nchunk + c];
        cacc += pctx[(size_t)(gw * nchunk + c) * HD + lane];
    }
    ctxout[gw * HD + lane] = cacc / lacc;
}

// -------- kernel 4: out = ctx @ c_proj_w + c_proj_b, 4-way k-sliced --------
__global__ __launch_bounds__(256) void proj_kernel(const float* __restrict__ ctx,
                                                   const float* __restrict__ W,
                                                   const float* __restrict__ bias,
                                                   float* __restrict__ out) {
    const int b = blockIdx.y;
    const int jj = threadIdx.x & 63;
    const int j = blockIdx.x * 64 + jj;
    const int ksl = threadIdx.x >> 6;
    __shared__ float h[E_DIM];
    for (int i = threadIdx.x; i < E_DIM; i += 256) h[i] = ctx[b * E_DIM + i];
    __syncthreads();
    float acc = 0.f;
    const int k0 = ksl * 256;
    #pragma unroll 8
    for (int k = k0; k < k0 + 256; ++k) acc = fmaf(h[k], W[(size_t)k * E_DIM + j], acc);
    __shared__ float red[4][64];
    red[ksl][jj] = acc;
    __syncthreads();
    if (ksl == 0)
        out[b * E_DIM + j] = acc + red[1][jj] + red[2][jj] + red[3][jj] + bias[j];
}

extern "C" void kernel_launch(void* const* d_in, const int* in_sizes, int n_in,
                              void* d_out, int out_size, void* d_ws, size_t ws_size,
                              hipStream_t stream) {
    const float* hs      = (const float*)d_in[0];
    const float* kcache  = (const float*)d_in[1];
    const float* vcache  = (const float*)d_in[2];
    const int*   mask    = (const int*)d_in[3];
    const float* attn_w  = (const float*)d_in[4];
    const float* attn_b  = (const float*)d_in[5];
    const float* proj_w  = (const float*)d_in[6];
    const float* proj_b  = (const float*)d_in[7];
    const float* bias0   = (const float*)d_in[8];

    float* out0 = (float*)d_out;
    float* newk = out0 + (size_t)BATCH * E_DIM;
    float* newv = newk + (size_t)BATCH * SEQ * E_DIM;

    // Workspace (floats): qkv 98304 | ctxbuf 32768 | mbias 131072 |
    //                     pl 32768 | pctx 2097152 | lastbuf 32  -> ~9.6 MB
    float* ws = (float*)d_ws;
    float* qkv     = ws;
    float* ctxbuf  = qkv + 98304;
    float* mbias   = ctxbuf + 32768;
    float* pl      = mbias + 131072;
    float* pctx    = pl + 32768;
    int*   lastbuf = (int*)(pctx + 2097152);

    prep_kernel<<<dim3(BATCH), dim3(256), 0, stream>>>(mask, bias0, lastbuf, mbias);
    qkv_kernel<<<dim3(48, BATCH), dim3(256), 0, stream>>>(hs, attn_w, attn_b, qkv);
    attn_kv_kernel<<<dim3(NBLK), dim3(256), 0, stream>>>(
        kcache, vcache, mbias, qkv, lastbuf, newk, newv, pl, pctx);
    reduce_kernel<<<dim3((BATCH * NH * 64 + 255) / 256), dim3(256), 0, stream>>>(
        pl, pctx, ctxbuf, NCH);
    proj_kernel<<<dim3(16, BATCH), dim3(256), 0, stream>>>(ctxbuf, proj_w, proj_b, out0);
}

// Round 8
// 519.056 us; speedup vs baseline: 1.2932x; 1.2932x over previous
//
#include <hip/hip_runtime.h>
#include <hip/hip_bf16.h>

typedef float f32x4 __attribute__((ext_vector_type(4)));

#define BATCH 32
#define S_LEN 4095
#define SEQ   4096
#define E_DIM 1024
#define NH    16
#define HD    64
#define CHUNK 128
#define NCH   (SEQ / CHUNK)   // 32

// -------- kernel 0: fused {prep (mask/bias/last), qkv GEMM} --------
// blocks [0,48*BATCH): qkv ; blocks [48*BATCH, 48*BATCH+BATCH): prep
__global__ __launch_bounds__(256) void head_kernel(
    const int* __restrict__ mask, const float* __restrict__ bias,
    const float* __restrict__ hs, const float* __restrict__ W,
    const float* __restrict__ wb,
    int* __restrict__ lastbuf, float* __restrict__ mbias,
    float* __restrict__ qkv) {
    const int blk = blockIdx.x;
    const int t = threadIdx.x;
    if (blk < 48 * BATCH) {
        const int b = blk / 48;
        const int jblk = blk % 48;
        const int jj = t & 63;
        const int j = jblk * 64 + jj;
        const int ksl = t >> 6;
        __shared__ float h[E_DIM];
        for (int i = t; i < E_DIM; i += 256) h[i] = hs[b * E_DIM + i];
        __syncthreads();
        float acc = 0.f;
        const int k0 = ksl * 256;
        #pragma unroll 8
        for (int k = k0; k < k0 + 256; ++k) acc = fmaf(h[k], W[(size_t)k * 3072 + j], acc);
        __shared__ float red[4][64];
        red[ksl][jj] = acc;
        __syncthreads();
        if (ksl == 0)
            qkv[b * 3072 + j] = acc + red[1][jj] + red[2][jj] + red[3][jj] + wb[j];
    } else {
        const int b = blk - 48 * BATCH;
        int best = -1;
        for (int s = t; s < SEQ; s += 256) {
            int mv = mask[b * SEQ + s];
            mbias[b * SEQ + s] = mv ? bias[s] : -1.0e9f;
            if (mv) best = max(best, s);
        }
        __shared__ int red[256];
        red[t] = best;
        __syncthreads();
        for (int o = 128; o > 0; o >>= 1) {
            if (t < o) red[t] = max(red[t], red[t + o]);
            __syncthreads();
        }
        if (t == 0) lastbuf[b] = (red[0] < 0) ? (SEQ - 1) : red[0];
    }
}

// -------- kernel 2a: K-phase — cache-append K + exp-weights --------
__global__ __launch_bounds__(256) void attn_k_kernel(
    const float* __restrict__ kcache, const float* __restrict__ mbias,
    const float* __restrict__ qkv, const int* __restrict__ lastbuf,
    float* __restrict__ newk, float* __restrict__ wts) {
    const int c = blockIdx.x;       // 0..NCH-1
    const int b = blockIdx.y;
    const int t = threadIdx.x;
    const int wave = t >> 6;
    const int lane = t & 63;
    const int head = wave * 4 + (lane >> 4);
    const int lig = lane & 15;
    const int col = head * HD + lig * 4;
    const int last = lastbuf[b];

    const f32x4 q4 = *(const f32x4*)(qkv + b * 3072 + col);
    const f32x4 kn4 = *(const f32x4*)(qkv + b * 3072 + 1024 + col);
    const float* kb = kcache + (size_t)b * S_LEN * E_DIM;
    float* nkb = newk + (size_t)b * SEQ * E_DIM;
    const float* mbb = mbias + b * SEQ;

    __shared__ float sc[NH][CHUNK];
    const int s0 = c * CHUNK;
    const bool clean = (s0 + CHUNK <= S_LEN) && (last < s0 || last >= s0 + CHUNK);

    if (clean) {
        for (int r = 0; r < CHUNK; r += 8) {
            f32x4 kk[8];
            #pragma unroll
            for (int u = 0; u < 8; ++u)
                kk[u] = *(const f32x4*)(kb + (size_t)(s0 + r + u) * E_DIM + col);
            #pragma unroll
            for (int u = 0; u < 8; ++u)
                *(f32x4*)(nkb + (size_t)(s0 + r + u) * E_DIM + col) = kk[u];
            #pragma unroll
            for (int u = 0; u < 8; ++u) {
                float p = kk[u][0] * q4[0] + kk[u][1] * q4[1] + kk[u][2] * q4[2] + kk[u][3] * q4[3];
                p += __shfl_xor(p, 1);
                p += __shfl_xor(p, 2);
                p += __shfl_xor(p, 4);
                p += __shfl_xor(p, 8);
                if (lig == 0)
                    sc[head][r + u] = __expf(fmaf(p, 0.125f, mbb[s0 + r + u]));
            }
        }
    } else {
        for (int r = 0; r < CHUNK; ++r) {
            const int s = s0 + r;
            f32x4 kk;
            if (s == last) kk = kn4;
            else if (s < S_LEN) kk = *(const f32x4*)(kb + (size_t)s * E_DIM + col);
            else kk = (f32x4){0.f, 0.f, 0.f, 0.f};
            *(f32x4*)(nkb + (size_t)s * E_DIM + col) = kk;
            float p = kk[0] * q4[0] + kk[1] * q4[1] + kk[2] * q4[2] + kk[3] * q4[3];
            p += __shfl_xor(p, 1);
            p += __shfl_xor(p, 2);
            p += __shfl_xor(p, 4);
            p += __shfl_xor(p, 8);
            if (lig == 0)
                sc[head][r] = __expf(fmaf(p, 0.125f, mbb[s]));
        }
    }
    __syncthreads();
    // block-private contiguous layout: wts[(b*NCH+c)*NH*CHUNK + h*CHUNK + r]
    float* wblk = wts + (size_t)(b * NCH + c) * (NH * CHUNK);
    for (int idx = t; idx < NH * CHUNK; idx += 256)
        wblk[idx] = sc[idx / CHUNK][idx % CHUNK];
}

// -------- kernel 2b: V-phase — cache-append V + weighted accumulate --------
__global__ __launch_bounds__(256) void attn_v_kernel(
    const float* __restrict__ vcache, const float* __restrict__ wts,
    const float* __restrict__ qkv, const int* __restrict__ lastbuf,
    float* __restrict__ newv, float* __restrict__ pl, float* __restrict__ pctx) {
    const int c = blockIdx.x;
    const int b = blockIdx.y;
    const int t = threadIdx.x;
    const int wave = t >> 6;
    const int lane = t & 63;
    const int head = wave * 4 + (lane >> 4);
    const int lig = lane & 15;
    const int col = head * HD + lig * 4;
    const int last = lastbuf[b];

    const f32x4 vn4 = *(const f32x4*)(qkv + b * 3072 + 2048 + col);
    const float* vb = vcache + (size_t)b * S_LEN * E_DIM;
    float* nvb = newv + (size_t)b * SEQ * E_DIM;

    __shared__ float w_s[NH][CHUNK];
    const float* wblk = wts + (size_t)(b * NCH + c) * (NH * CHUNK);
    for (int idx = t; idx < NH * CHUNK; idx += 256)
        w_s[idx / CHUNK][idx % CHUNK] = wblk[idx];
    __syncthreads();

    float l = 0.f;
    f32x4 acc = (f32x4){0.f, 0.f, 0.f, 0.f};
    const int s0 = c * CHUNK;
    const bool clean = (s0 + CHUNK <= S_LEN) && (last < s0 || last >= s0 + CHUNK);

    if (clean) {
        for (int r = 0; r < CHUNK; r += 8) {
            f32x4 vv[8];
            #pragma unroll
            for (int u = 0; u < 8; ++u)
                vv[u] = *(const f32x4*)(vb + (size_t)(s0 + r + u) * E_DIM + col);
            #pragma unroll
            for (int u = 0; u < 8; ++u)
                *(f32x4*)(nvb + (size_t)(s0 + r + u) * E_DIM + col) = vv[u];
            #pragma unroll
            for (int u = 0; u < 8; ++u) {
                const float w = w_s[head][r + u];
                l += w;
                acc += vv[u] * w;
            }
        }
    } else {
        for (int r = 0; r < CHUNK; ++r) {
            const int s = s0 + r;
            f32x4 vv;
            if (s == last) vv = vn4;
            else if (s < S_LEN) vv = *(const f32x4*)(vb + (size_t)s * E_DIM + col);
            else vv = (f32x4){0.f, 0.f, 0.f, 0.f};
            *(f32x4*)(nvb + (size_t)s * E_DIM + col) = vv;
            const float w = w_s[head][r];
            l += w;
            acc += vv * w;
        }
    }

    const int pidx = (b * NH + head) * NCH + c;
    if (lig == 0) pl[pidx] = l;
    *(f32x4*)(pctx + (size_t)pidx * HD + lig * 4) = acc;
}

// -------- kernel 3: reduce chunk partials per (b,h) --------
__global__ __launch_bounds__(256) void reduce_kernel(const float* __restrict__ pl,
                                                     const float* __restrict__ pctx,
                                                     float* __restrict__ ctxout,
                                                     int nchunk) {
    const int gw = (blockIdx.x * blockDim.x + threadIdx.x) >> 6;
    const int lane = threadIdx.x & 63;
    if (gw >= BATCH * NH) return;
    float lacc = 0.f, cacc = 0.f;
    for (int c = 0; c < nchunk; ++c) {
        lacc += pl[gw * nchunk + c];
        cacc += pctx[(size_t)(gw * nchunk + c) * HD + lane];
    }
    ctxout[gw * HD + lane] = cacc / lacc;
}

// -------- kernel 4: out = ctx @ c_proj_w + c_proj_b, 4-way k-sliced --------
__global__ __launch_bounds__(256) void proj_kernel(const float* __restrict__ ctx,
                                                   const float* __restrict__ W,
                                                   const float* __restrict__ bias,
                                                   float* __restrict__ out) {
    const int b = blockIdx.y;
    const int jj = threadIdx.x & 63;
    const int j = blockIdx.x * 64 + jj;
    const int ksl = threadIdx.x >> 6;
    __shared__ float h[E_DIM];
    for (int i = threadIdx.x; i < E_DIM; i += 256) h[i] = ctx[b * E_DIM + i];
    __syncthreads();
    float acc = 0.f;
    const int k0 = ksl * 256;
    #pragma unroll 8
    for (int k = k0; k < k0 + 256; ++k) acc = fmaf(h[k], W[(size_t)k * E_DIM + j], acc);
    __shared__ float red[4][64];
    red[ksl][jj] = acc;
    __syncthreads();
    if (ksl == 0)
        out[b * E_DIM + j] = acc + red[1][jj] + red[2][jj] + red[3][jj] + bias[j];
}

extern "C" void kernel_launch(void* const* d_in, const int* in_sizes, int n_in,
                              void* d_out, int out_size, void* d_ws, size_t ws_size,
                              hipStream_t stream) {
    const float* hs      = (const float*)d_in[0];
    const float* kcache  = (const float*)d_in[1];
    const float* vcache  = (const float*)d_in[2];
    const int*   mask    = (const int*)d_in[3];
    const float* attn_w  = (const float*)d_in[4];
    const float* attn_b  = (const float*)d_in[5];
    const float* proj_w  = (const float*)d_in[6];
    const float* proj_b  = (const float*)d_in[7];
    const float* bias0   = (const float*)d_in[8];

    float* out0 = (float*)d_out;
    float* newk = out0 + (size_t)BATCH * E_DIM;
    float* newv = newk + (size_t)BATCH * SEQ * E_DIM;

    // Workspace (floats): qkv 98304 | ctxbuf 32768 | mbias 131072 |
    //                     wts 2097152 | pl 16384 | pctx 1048576 | lastbuf 32
    float* ws = (float*)d_ws;
    float* qkv     = ws;
    float* ctxbuf  = qkv + 98304;
    float* mbias   = ctxbuf + 32768;
    float* wts     = mbias + 131072;
    float* pl      = wts + 2097152;
    float* pctx    = pl + 16384;
    int*   lastbuf = (int*)(pctx + 1048576);

    head_kernel<<<dim3(48 * BATCH + BATCH), dim3(256), 0, stream>>>(
        mask, bias0, hs, attn_w, attn_b, lastbuf, mbias, qkv);
    attn_k_kernel<<<dim3(NCH, BATCH), dim3(256), 0, stream>>>(
        kcache, mbias, qkv, lastbuf, newk, wts);
    attn_v_kernel<<<dim3(NCH, BATCH), dim3(256), 0, stream>>>(
        vcache, wts, qkv, lastbuf, newv, pl, pctx);
    reduce_kernel<<<dim3((BATCH * NH * 64 + 255) / 256), dim3(256), 0, stream>>>(
        pl, pctx, ctxbuf, NCH);
    proj_kernel<<<dim3(16, BATCH), dim3(256), 0, stream>>>(ctxbuf, proj_w, proj_b, out0);
}

// Round 9
// 461.543 us; speedup vs baseline: 1.4544x; 1.1246x over previous
//
#include <hip/hip_runtime.h>
#include <hip/hip_bf16.h>

typedef float f32x4 __attribute__((ext_vector_type(4)));

#define BATCH 32
#define S_LEN 4095
#define SEQ   4096
#define E_DIM 1024
#define NH    16
#define HD    64
#define CHUNK 64
#define NCH   (SEQ / CHUNK)   // 64

__device__ __forceinline__ f32x4 ntload4(const float* p) {
    return __builtin_nontemporal_load((const f32x4*)p);
}
__device__ __forceinline__ void ntstore4(float* p, f32x4 v) {
    __builtin_nontemporal_store(v, (f32x4*)p);
}

// -------- kernel 0: fused {qkv GEMM, prep(mask/bias/last)} --------
// blocks [0,48*BATCH): qkv ; blocks [48*BATCH, 48*BATCH+BATCH): prep
__global__ __launch_bounds__(256) void head_kernel(
    const int* __restrict__ mask, const float* __restrict__ bias,
    const float* __restrict__ hs, const float* __restrict__ W,
    const float* __restrict__ wb,
    int* __restrict__ lastbuf, float* __restrict__ mbias,
    float* __restrict__ qkv) {
    const int blk = blockIdx.x;
    const int t = threadIdx.x;
    if (blk < 48 * BATCH) {
        const int b = blk / 48;
        const int jblk = blk % 48;
        const int jj = t & 63;
        const int j = jblk * 64 + jj;
        const int ksl = t >> 6;
        __shared__ float h[E_DIM];
        for (int i = t; i < E_DIM; i += 256) h[i] = hs[b * E_DIM + i];
        __syncthreads();
        float acc = 0.f;
        const int k0 = ksl * 256;
        #pragma unroll 8
        for (int k = k0; k < k0 + 256; ++k) acc = fmaf(h[k], W[(size_t)k * 3072 + j], acc);
        __shared__ float red[4][64];
        red[ksl][jj] = acc;
        __syncthreads();
        if (ksl == 0)
            qkv[b * 3072 + j] = acc + red[1][jj] + red[2][jj] + red[3][jj] + wb[j];
    } else {
        const int b = blk - 48 * BATCH;
        int best = -1;
        for (int s = t; s < SEQ; s += 256) {
            int mv = mask[b * SEQ + s];
            mbias[b * SEQ + s] = mv ? bias[s] : -1.0e9f;
            if (mv) best = max(best, s);
        }
        __shared__ int red[256];
        red[t] = best;
        __syncthreads();
        for (int o = 128; o > 0; o >>= 1) {
            if (t < o) red[t] = max(red[t], red[t + o]);
            __syncthreads();
        }
        if (t == 0) lastbuf[b] = (red[0] < 0) ? (SEQ - 1) : red[0];
    }
}

// -------- kernel 2a: K-phase — cache-append K + exp-weights --------
__global__ __launch_bounds__(256) void attn_k_kernel(
    const float* __restrict__ kcache, const float* __restrict__ mbias,
    const float* __restrict__ qkv, const int* __restrict__ lastbuf,
    float* __restrict__ newk, float* __restrict__ wts) {
    const int c = blockIdx.x;       // 0..NCH-1
    const int b = blockIdx.y;
    const int t = threadIdx.x;
    const int wave = t >> 6;
    const int lane = t & 63;
    const int head = wave * 4 + (lane >> 4);
    const int lig = lane & 15;
    const int col = head * HD + lig * 4;
    const int last = lastbuf[b];

    const f32x4 q4 = *(const f32x4*)(qkv + b * 3072 + col);
    const f32x4 kn4 = *(const f32x4*)(qkv + b * 3072 + 1024 + col);
    const float* kb = kcache + (size_t)b * S_LEN * E_DIM;
    float* nkb = newk + (size_t)b * SEQ * E_DIM;
    const float* mbb = mbias + b * SEQ;

    __shared__ float sc[NH][CHUNK];
    const int s0 = c * CHUNK;
    const bool clean = (s0 + CHUNK <= S_LEN) && (last < s0 || last >= s0 + CHUNK);

    if (clean) {
        for (int r = 0; r < CHUNK; r += 8) {
            f32x4 kk[8];
            #pragma unroll
            for (int u = 0; u < 8; ++u)
                kk[u] = ntload4(kb + (size_t)(s0 + r + u) * E_DIM + col);
            #pragma unroll
            for (int u = 0; u < 8; ++u)
                ntstore4(nkb + (size_t)(s0 + r + u) * E_DIM + col, kk[u]);
            #pragma unroll
            for (int u = 0; u < 8; ++u) {
                float p = kk[u][0] * q4[0] + kk[u][1] * q4[1] + kk[u][2] * q4[2] + kk[u][3] * q4[3];
                p += __shfl_xor(p, 1);
                p += __shfl_xor(p, 2);
                p += __shfl_xor(p, 4);
                p += __shfl_xor(p, 8);
                if (lig == 0)
                    sc[head][r + u] = __expf(fmaf(p, 0.125f, mbb[s0 + r + u]));
            }
        }
    } else {
        for (int r = 0; r < CHUNK; ++r) {
            const int s = s0 + r;
            f32x4 kk;
            if (s == last) kk = kn4;
            else if (s < S_LEN) kk = ntload4(kb + (size_t)s * E_DIM + col);
            else kk = (f32x4){0.f, 0.f, 0.f, 0.f};
            ntstore4(nkb + (size_t)s * E_DIM + col, kk);
            float p = kk[0] * q4[0] + kk[1] * q4[1] + kk[2] * q4[2] + kk[3] * q4[3];
            p += __shfl_xor(p, 1);
            p += __shfl_xor(p, 2);
            p += __shfl_xor(p, 4);
            p += __shfl_xor(p, 8);
            if (lig == 0)
                sc[head][r] = __expf(fmaf(p, 0.125f, mbb[s]));
        }
    }
    __syncthreads();
    // block-private contiguous layout: wts[(b*NCH+c)*NH*CHUNK + h*CHUNK + r]
    float* wblk = wts + (size_t)(b * NCH + c) * (NH * CHUNK);
    for (int idx = t; idx < NH * CHUNK; idx += 256)
        wblk[idx] = sc[idx >> 6][idx & 63];
}

// -------- kernel 2b: V-phase — cache-append V + weighted accumulate --------
__global__ __launch_bounds__(256) void attn_v_kernel(
    const float* __restrict__ vcache, const float* __restrict__ wts,
    const float* __restrict__ qkv, const int* __restrict__ lastbuf,
    float* __restrict__ newv, float* __restrict__ pl, float* __restrict__ pctx) {
    const int c = blockIdx.x;
    const int b = blockIdx.y;
    const int t = threadIdx.x;
    const int wave = t >> 6;
    const int lane = t & 63;
    const int head = wave * 4 + (lane >> 4);
    const int lig = lane & 15;
    const int col = head * HD + lig * 4;
    const int last = lastbuf[b];

    const f32x4 vn4 = *(const f32x4*)(qkv + b * 3072 + 2048 + col);
    const float* vb = vcache + (size_t)b * S_LEN * E_DIM;
    float* nvb = newv + (size_t)b * SEQ * E_DIM;

    __shared__ float w_s[NH][CHUNK];
    const float* wblk = wts + (size_t)(b * NCH + c) * (NH * CHUNK);
    for (int idx = t; idx < NH * CHUNK; idx += 256)
        w_s[idx >> 6][idx & 63] = wblk[idx];
    __syncthreads();

    float l = 0.f;
    f32x4 acc = (f32x4){0.f, 0.f, 0.f, 0.f};
    const int s0 = c * CHUNK;
    const bool clean = (s0 + CHUNK <= S_LEN) && (last < s0 || last >= s0 + CHUNK);

    if (clean) {
        for (int r = 0; r < CHUNK; r += 8) {
            f32x4 vv[8];
            #pragma unroll
            for (int u = 0; u < 8; ++u)
                vv[u] = ntload4(vb + (size_t)(s0 + r + u) * E_DIM + col);
            #pragma unroll
            for (int u = 0; u < 8; ++u)
                ntstore4(nvb + (size_t)(s0 + r + u) * E_DIM + col, vv[u]);
            #pragma unroll
            for (int u = 0; u < 8; ++u) {
                const float w = w_s[head][r + u];
                l += w;
                acc += vv[u] * w;
            }
        }
    } else {
        for (int r = 0; r < CHUNK; ++r) {
            const int s = s0 + r;
            f32x4 vv;
            if (s == last) vv = vn4;
            else if (s < S_LEN) vv = ntload4(vb + (size_t)s * E_DIM + col);
            else vv = (f32x4){0.f, 0.f, 0.f, 0.f};
            ntstore4(nvb + (size_t)s * E_DIM + col, vv);
            const float w = w_s[head][r];
            l += w;
            acc += vv * w;
        }
    }

    const int pidx = (b * NH + head) * NCH + c;
    if (lig == 0) pl[pidx] = l;
    *(f32x4*)(pctx + (size_t)pidx * HD + lig * 4) = acc;
}

// -------- kernel 3: reduce chunk partials per (b,h) --------
__global__ __launch_bounds__(256) void reduce_kernel(const float* __restrict__ pl,
                                                     const float* __restrict__ pctx,
                                                     float* __restrict__ ctxout,
                                                     int nchunk) {
    const int gw = (blockIdx.x * blockDim.x + threadIdx.x) >> 6;
    const int lane = threadIdx.x & 63;
    if (gw >= BATCH * NH) return;
    float lacc = 0.f, cacc = 0.f;
    for (int c = 0; c < nchunk; ++c) {
        lacc += pl[gw * nchunk + c];
        cacc += pctx[(size_t)(gw * nchunk + c) * HD + lane];
    }
    ctxout[gw * HD + lane] = cacc / lacc;
}

// -------- kernel 4: out = ctx @ c_proj_w + c_proj_b, 4-way k-sliced --------
__global__ __launch_bounds__(256) void proj_kernel(const float* __restrict__ ctx,
                                                   const float* __restrict__ W,
                                                   const float* __restrict__ bias,
                                                   float* __restrict__ out) {
    const int b = blockIdx.y;
    const int jj = threadIdx.x & 63;
    const int j = blockIdx.x * 64 + jj;
    const int ksl = threadIdx.x >> 6;
    __shared__ float h[E_DIM];
    for (int i = threadIdx.x; i < E_DIM; i += 256) h[i] = ctx[b * E_DIM + i];
    __syncthreads();
    float acc = 0.f;
    const int k0 = ksl * 256;
    #pragma unroll 8
    for (int k = k0; k < k0 + 256; ++k) acc = fmaf(h[k], W[(size_t)k * E_DIM + j], acc);
    __shared__ float red[4][64];
    red[ksl][jj] = acc;
    __syncthreads();
    if (ksl == 0)
        out[b * E_DIM + j] = acc + red[1][jj] + red[2][jj] + red[3][jj] + bias[j];
}

extern "C" void kernel_launch(void* const* d_in, const int* in_sizes, int n_in,
                              void* d_out, int out_size, void* d_ws, size_t ws_size,
                              hipStream_t stream) {
    const float* hs      = (const float*)d_in[0];
    const float* kcache  = (const float*)d_in[1];
    const float* vcache  = (const float*)d_in[2];
    const int*   mask    = (const int*)d_in[3];
    const float* attn_w  = (const float*)d_in[4];
    const float* attn_b  = (const float*)d_in[5];
    const float* proj_w  = (const float*)d_in[6];
    const float* proj_b  = (const float*)d_in[7];
    const float* bias0   = (const float*)d_in[8];

    float* out0 = (float*)d_out;
    float* newk = out0 + (size_t)BATCH * E_DIM;
    float* newv = newk + (size_t)BATCH * SEQ * E_DIM;

    // Workspace (floats): qkv 98304 | ctxbuf 32768 | mbias 131072 |
    //                     wts 2097152 | pl 32768 | pctx 2097152 | lastbuf 32
    float* ws = (float*)d_ws;
    float* qkv     = ws;
    float* ctxbuf  = qkv + 98304;
    float* mbias   = ctxbuf + 32768;
    float* wts     = mbias + 131072;
    float* pl      = wts + 2097152;
    float* pctx    = pl + 32768;
    int*   lastbuf = (int*)(pctx + 2097152);

    head_kernel<<<dim3(48 * BATCH + BATCH), dim3(256), 0, stream>>>(
        mask, bias0, hs, attn_w, attn_b, lastbuf, mbias, qkv);
    attn_k_kernel<<<dim3(NCH, BATCH), dim3(256), 0, stream>>>(
        kcache, mbias, qkv, lastbuf, newk, wts);
    attn_v_kernel<<<dim3(NCH, BATCH), dim3(256), 0, stream>>>(
        vcache, wts, qkv, lastbuf, newv, pl, pctx);
    reduce_kernel<<<dim3((BATCH * NH * 64 + 255) / 256), dim3(256), 0, stream>>>(
        pl, pctx, ctxbuf, NCH);
    proj_kernel<<<dim3(16, BATCH), dim3(256), 0, stream>>>(ctxbuf, proj_w, proj_b, out0);
}

// Round 10
// 444.441 us; speedup vs baseline: 1.5103x; 1.0385x over previous
//
#include <hip/hip_runtime.h>
#include <hip/hip_bf16.h>

typedef float f32x4 __attribute__((ext_vector_type(4)));

#define BATCH 32
#define S_LEN 4095
#define SEQ   4096
#define E_DIM 1024
#define NH    16
#define HD    64
#define CHUNK 64
#define NCH   (SEQ / CHUNK)   // 64
#define QB    4               // batches per GEMM block

__device__ __forceinline__ f32x4 ntload4(const float* p) {
    return __builtin_nontemporal_load((const f32x4*)p);
}
__device__ __forceinline__ void ntstore4(float* p, f32x4 v) {
    __builtin_nontemporal_store(v, (f32x4*)p);
}

// -------- kernel 0: fused {qkv GEMM (4 batches/block), prep(mask/bias/last)} --------
// blocks [0, 8*48): qkv ; blocks [8*48, 8*48+BATCH): prep
__global__ __launch_bounds__(256) void head_kernel(
    const int* __restrict__ mask, const float* __restrict__ bias,
    const float* __restrict__ hs, const float* __restrict__ W,
    const float* __restrict__ wb,
    int* __restrict__ lastbuf, float* __restrict__ mbias,
    float* __restrict__ qkv) {
    const int blk = blockIdx.x;
    const int t = threadIdx.x;
    if (blk < 8 * 48) {
        const int bg = blk / 48;        // batch group 0..7
        const int jblk = blk % 48;
        const int jj = t & 63;
        const int j = jblk * 64 + jj;
        const int ksl = t >> 6;         // 0..3
        __shared__ float h[QB][E_DIM];  // 16 KB
        for (int i = t; i < QB * E_DIM; i += 256)
            h[i >> 10][i & 1023] = hs[(size_t)(bg * QB + (i >> 10)) * E_DIM + (i & 1023)];
        __syncthreads();
        float acc[QB] = {0.f, 0.f, 0.f, 0.f};
        const int k0 = ksl * 256;
        #pragma unroll 8
        for (int k = k0; k < k0 + 256; ++k) {
            const float w = W[(size_t)k * 3072 + j];
            #pragma unroll
            for (int q = 0; q < QB; ++q) acc[q] = fmaf(h[q][k], w, acc[q]);
        }
        __shared__ float red[4][64][QB];  // 4 KB
        #pragma unroll
        for (int q = 0; q < QB; ++q) red[ksl][jj][q] = acc[q];
        __syncthreads();
        if (ksl == 0) {
            #pragma unroll
            for (int q = 0; q < QB; ++q)
                qkv[(size_t)(bg * QB + q) * 3072 + j] =
                    red[0][jj][q] + red[1][jj][q] + red[2][jj][q] + red[3][jj][q] + wb[j];
        }
    } else {
        const int b = blk - 8 * 48;
        int best = -1;
        for (int s = t; s < SEQ; s += 256) {
            int mv = mask[b * SEQ + s];
            mbias[b * SEQ + s] = mv ? bias[s] : -1.0e9f;
            if (mv) best = max(best, s);
        }
        __shared__ int red[256];
        red[t] = best;
        __syncthreads();
        for (int o = 128; o > 0; o >>= 1) {
            if (t < o) red[t] = max(red[t], red[t + o]);
            __syncthreads();
        }
        if (t == 0) lastbuf[b] = (red[0] < 0) ? (SEQ - 1) : red[0];
    }
}

// -------- kernel 2: fused K-phase + V-phase per chunk (non-persistent) --------
__global__ __launch_bounds__(256) void attn_kv_kernel(
    const float* __restrict__ kcache, const float* __restrict__ vcache,
    const float* __restrict__ mbias, const float* __restrict__ qkv,
    const int* __restrict__ lastbuf,
    float* __restrict__ newk, float* __restrict__ newv,
    float* __restrict__ pl, float* __restrict__ pctx) {
    const int c = blockIdx.x;       // 0..NCH-1
    const int b = blockIdx.y;
    const int t = threadIdx.x;
    const int wave = t >> 6;
    const int lane = t & 63;
    const int head = wave * 4 + (lane >> 4);
    const int lig = lane & 15;
    const int col = head * HD + lig * 4;
    const int last = lastbuf[b];

    const float* mbb = mbias + b * SEQ;
    __shared__ float w_s[NH][CHUNK];
    const int s0 = c * CHUNK;
    const bool clean = (s0 + CHUNK <= S_LEN) && (last < s0 || last >= s0 + CHUNK);

    // ---------------- K phase ----------------
    {
        const f32x4 q4 = *(const f32x4*)(qkv + b * 3072 + col);
        const f32x4 kn4 = *(const f32x4*)(qkv + b * 3072 + 1024 + col);
        const float* kb = kcache + (size_t)b * S_LEN * E_DIM;
        float* nkb = newk + (size_t)b * SEQ * E_DIM;

        if (clean) {
            for (int r = 0; r < CHUNK; r += 8) {
                f32x4 kk[8];
                #pragma unroll
                for (int u = 0; u < 8; ++u)
                    kk[u] = ntload4(kb + (size_t)(s0 + r + u) * E_DIM + col);
                #pragma unroll
                for (int u = 0; u < 8; ++u)
                    ntstore4(nkb + (size_t)(s0 + r + u) * E_DIM + col, kk[u]);
                #pragma unroll
                for (int u = 0; u < 8; ++u) {
                    float p = kk[u][0] * q4[0] + kk[u][1] * q4[1] + kk[u][2] * q4[2] + kk[u][3] * q4[3];
                    p += __shfl_xor(p, 1);
                    p += __shfl_xor(p, 2);
                    p += __shfl_xor(p, 4);
                    p += __shfl_xor(p, 8);
                    if (lig == 0)
                        w_s[head][r + u] = __expf(fmaf(p, 0.125f, mbb[s0 + r + u]));
                }
            }
        } else {
            for (int r = 0; r < CHUNK; ++r) {
                const int s = s0 + r;
                f32x4 kk;
                if (s == last) kk = kn4;
                else if (s < S_LEN) kk = ntload4(kb + (size_t)s * E_DIM + col);
                else kk = (f32x4){0.f, 0.f, 0.f, 0.f};
                ntstore4(nkb + (size_t)s * E_DIM + col, kk);
                float p = kk[0] * q4[0] + kk[1] * q4[1] + kk[2] * q4[2] + kk[3] * q4[3];
                p += __shfl_xor(p, 1);
                p += __shfl_xor(p, 2);
                p += __shfl_xor(p, 4);
                p += __shfl_xor(p, 8);
                if (lig == 0)
                    w_s[head][r] = __expf(fmaf(p, 0.125f, mbb[s]));
            }
        }
    }
    __syncthreads();

    // ---------------- V phase ----------------
    {
        const f32x4 vn4 = *(const f32x4*)(qkv + b * 3072 + 2048 + col);
        const float* vb = vcache + (size_t)b * S_LEN * E_DIM;
        float* nvb = newv + (size_t)b * SEQ * E_DIM;

        float l = 0.f;
        f32x4 acc = (f32x4){0.f, 0.f, 0.f, 0.f};
        if (clean) {
            for (int r = 0; r < CHUNK; r += 8) {
                f32x4 vv[8];
                #pragma unroll
                for (int u = 0; u < 8; ++u)
                    vv[u] = ntload4(vb + (size_t)(s0 + r + u) * E_DIM + col);
                #pragma unroll
                for (int u = 0; u < 8; ++u)
                    ntstore4(nvb + (size_t)(s0 + r + u) * E_DIM + col, vv[u]);
                #pragma unroll
                for (int u = 0; u < 8; ++u) {
                    const float w = w_s[head][r + u];
                    l += w;
                    acc += vv[u] * w;
                }
            }
        } else {
            for (int r = 0; r < CHUNK; ++r) {
                const int s = s0 + r;
                f32x4 vv;
                if (s == last) vv = vn4;
                else if (s < S_LEN) vv = ntload4(vb + (size_t)s * E_DIM + col);
                else vv = (f32x4){0.f, 0.f, 0.f, 0.f};
                ntstore4(nvb + (size_t)s * E_DIM + col, vv);
                const float w = w_s[head][r];
                l += w;
                acc += vv * w;
            }
        }

        const int pidx = (b * NH + head) * NCH + c;
        if (lig == 0) pl[pidx] = l;
        *(f32x4*)(pctx + (size_t)pidx * HD + lig * 4) = acc;
    }
}

// -------- kernel 3: reduce chunk partials per (b,h) --------
__global__ __launch_bounds__(256) void reduce_kernel(const float* __restrict__ pl,
                                                     const float* __restrict__ pctx,
                                                     float* __restrict__ ctxout,
                                                     int nchunk) {
    const int gw = (blockIdx.x * blockDim.x + threadIdx.x) >> 6;
    const int lane = threadIdx.x & 63;
    if (gw >= BATCH * NH) return;
    float lacc = 0.f, cacc = 0.f;
    for (int c = 0; c < nchunk; ++c) {
        lacc += pl[gw * nchunk + c];
        cacc += pctx[(size_t)(gw * nchunk + c) * HD + lane];
    }
    ctxout[gw * HD + lane] = cacc / lacc;
}

// -------- kernel 4: out = ctx @ c_proj_w + c_proj_b, 4 batches/block --------
__global__ __launch_bounds__(256) void proj_kernel(const float* __restrict__ ctx,
                                                   const float* __restrict__ W,
                                                   const float* __restrict__ bias,
                                                   float* __restrict__ out) {
    const int bg = blockIdx.y;       // batch group 0..7
    const int jblk = blockIdx.x;     // 0..15
    const int t = threadIdx.x;
    const int jj = t & 63;
    const int j = jblk * 64 + jj;
    const int ksl = t >> 6;
    __shared__ float h[QB][E_DIM];   // 16 KB
    for (int i = t; i < QB * E_DIM; i += 256)
        h[i >> 10][i & 1023] = ctx[(size_t)(bg * QB + (i >> 10)) * E_DIM + (i & 1023)];
    __syncthreads();
    float acc[QB] = {0.f, 0.f, 0.f, 0.f};
    const int k0 = ksl * 256;
    #pragma unroll 8
    for (int k = k0; k < k0 + 256; ++k) {
        const float w = W[(size_t)k * E_DIM + j];
        #pragma unroll
        for (int q = 0; q < QB; ++q) acc[q] = fmaf(h[q][k], w, acc[q]);
    }
    __shared__ float red[4][64][QB];
    #pragma unroll
    for (int q = 0; q < QB; ++q) red[ksl][jj][q] = acc[q];
    __syncthreads();
    if (ksl == 0) {
        #pragma unroll
        for (int q = 0; q < QB; ++q)
            out[(size_t)(bg * QB + q) * E_DIM + j] =
                red[0][jj][q] + red[1][jj][q] + red[2][jj][q] + red[3][jj][q] + bias[j];
    }
}

extern "C" void kernel_launch(void* const* d_in, const int* in_sizes, int n_in,
                              void* d_out, int out_size, void* d_ws, size_t ws_size,
                              hipStream_t stream) {
    const float* hs      = (const float*)d_in[0];
    const float* kcache  = (const float*)d_in[1];
    const float* vcache  = (const float*)d_in[2];
    const int*   mask    = (const int*)d_in[3];
    const float* attn_w  = (const float*)d_in[4];
    const float* attn_b  = (const float*)d_in[5];
    const float* proj_w  = (const float*)d_in[6];
    const float* proj_b  = (const float*)d_in[7];
    const float* bias0   = (const float*)d_in[8];

    float* out0 = (float*)d_out;
    float* newk = out0 + (size_t)BATCH * E_DIM;
    float* newv = newk + (size_t)BATCH * SEQ * E_DIM;

    // Workspace (floats): qkv 98304 | ctxbuf 32768 | mbias 131072 |
    //                     pl 32768 | pctx 2097152 | lastbuf 32   (~9.4 MB)
    float* ws = (float*)d_ws;
    float* qkv     = ws;
    float* ctxbuf  = qkv + 98304;
    float* mbias   = ctxbuf + 32768;
    float* pl      = mbias + 131072;
    float* pctx    = pl + 32768;
    int*   lastbuf = (int*)(pctx + 2097152);

    head_kernel<<<dim3(8 * 48 + BATCH), dim3(256), 0, stream>>>(
        mask, bias0, hs, attn_w, attn_b, lastbuf, mbias, qkv);
    attn_kv_kernel<<<dim3(NCH, BATCH), dim3(256), 0, stream>>>(
        kcache, vcache, mbias, qkv, lastbuf, newk, newv, pl, pctx);
    reduce_kernel<<<dim3((BATCH * NH * 64 + 255) / 256), dim3(256), 0, stream>>>(
        pl, pctx, ctxbuf, NCH);
    proj_kernel<<<dim3(16, 8), dim3(256), 0, stream>>>(ctxbuf, proj_w, proj_b, out0);
}